// Round 2
// baseline (368.507 us; speedup 1.0000x reference)
//
#include <hip/hip_runtime.h>
#include <hip/hip_bf16.h>

typedef __attribute__((ext_vector_type(4))) float f32x4;
typedef __attribute__((ext_vector_type(8))) short bf16x8;
typedef __attribute__((ext_vector_type(4))) unsigned short us4;

#define NB 8192
#define KR 64
#define DD 128
#define NPAIR 2016

__device__ __forceinline__ unsigned short f2bf_rne(float x) {
    unsigned int u = __float_as_uint(x);
    u += 0x7fffu + ((u >> 16) & 1u);
    return (unsigned short)(u >> 16);
}

// One block per batch. 256 threads = 4 waves.
// Phase 1: load X (64x128 fp32) coalesced, split into bf16 hi/lo, store to
//          XOR-swizzled LDS (T2: ushort idx ^= (row&7)<<3  == byte ^= (row&7)<<4).
// Phase 2: wave w computes the 16x64 row-strip ti=w of C = X*X^T via
//          mfma_f32_16x16x32_bf16 with the 3-term split (hi*hi + hi*lo + lo*hi).
// Phase 3: write strictly-lower entries p = r*(r-1)/2 + c.
__global__ __launch_bounds__(256, 4) void dotint_kernel(const float* __restrict__ X,
                                                        float* __restrict__ out) {
    __shared__ unsigned short hi_s[KR * DD];
    __shared__ unsigned short lo_s[KR * DD];

    const int tid = threadIdx.x;
    const int b = blockIdx.x;
    const float* xb = X + (size_t)b * (KR * DD);

    // ---- Phase 1: load + hi/lo split ----
#pragma unroll
    for (int it = 0; it < 8; ++it) {
        const int e = it * 1024 + tid * 4;           // flat element index
        f32x4 v = *(const f32x4*)(xb + e);
        const int r = e >> 7;                        // row 0..63
        const int c = e & 127;                       // col, multiple of 4
        const int base = (r * DD + c) ^ ((r & 7) << 3);
        us4 h, l;
#pragma unroll
        for (int j = 0; j < 4; ++j) {
            const float x = v[j];
            const unsigned short hb = f2bf_rne(x);
            const float hf = __uint_as_float((unsigned int)hb << 16);
            const unsigned short lb = f2bf_rne(x - hf);
            h[j] = hb;
            l[j] = lb;
        }
        *(us4*)&hi_s[base] = h;
        *(us4*)&lo_s[base] = l;
    }
    __syncthreads();

    // ---- Phase 2: MFMA ----
    const int w = tid >> 6;          // wave id 0..3 -> tile row ti
    const int l = tid & 63;
    const int ti = w;
    const int arow = ti * 16 + (l & 15);
    const int kgrp = (l >> 4) * 8;   // k-offset of this lane's 8 contiguous k's

    f32x4 acc[4];
#pragma unroll
    for (int tj = 0; tj < 4; ++tj) acc[tj] = (f32x4){0.f, 0.f, 0.f, 0.f};

#pragma unroll
    for (int ks = 0; ks < 4; ++ks) {
        const int kc = ks * 32 + kgrp;
        const int aidx = (arow * DD + kc) ^ ((arow & 7) << 3);
        const bf16x8 a_hi = *(const bf16x8*)&hi_s[aidx];
        const bf16x8 a_lo = *(const bf16x8*)&lo_s[aidx];
#pragma unroll
        for (int tj = 0; tj < 4; ++tj) {
            const int brow = tj * 16 + (l & 15);
            const int bidx = (brow * DD + kc) ^ ((brow & 7) << 3);
            const bf16x8 b_hi = *(const bf16x8*)&hi_s[bidx];
            const bf16x8 b_lo = *(const bf16x8*)&lo_s[bidx];
            acc[tj] = __builtin_amdgcn_mfma_f32_16x16x32_bf16(a_hi, b_hi, acc[tj], 0, 0, 0);
            acc[tj] = __builtin_amdgcn_mfma_f32_16x16x32_bf16(a_hi, b_lo, acc[tj], 0, 0, 0);
            acc[tj] = __builtin_amdgcn_mfma_f32_16x16x32_bf16(a_lo, b_hi, acc[tj], 0, 0, 0);
        }
    }

    // ---- Phase 3: write strictly-lower triangle ----
    float* ob = out + (size_t)b * NPAIR;
    const int row0 = ti * 16 + (l >> 4) * 4;   // C/D layout: row=(lane>>4)*4+reg
    const int cl = l & 15;                     //             col=lane&15
#pragma unroll
    for (int tj = 0; tj < 4; ++tj) {
        const int c = tj * 16 + cl;
#pragma unroll
        for (int q = 0; q < 4; ++q) {
            const int r = row0 + q;
            if (r > c) ob[(r * (r - 1)) / 2 + c] = acc[tj][q];
        }
    }
}

extern "C" void kernel_launch(void* const* d_in, const int* in_sizes, int n_in,
                              void* d_out, int out_size, void* d_ws, size_t ws_size,
                              hipStream_t stream) {
    const float* X = (const float*)d_in[0];
    float* out = (float*)d_out;
    dotint_kernel<<<NB, 256, 0, stream>>>(X, out);
}

// Round 5
// 368.402 us; speedup vs baseline: 1.0003x; 1.0003x over previous
//
#include <hip/hip_runtime.h>
#include <hip/hip_bf16.h>

typedef __attribute__((ext_vector_type(4))) float f32x4;
typedef __attribute__((ext_vector_type(8))) short bf16x8;
typedef __attribute__((ext_vector_type(4))) unsigned short us4;

#define NB 8192
#define KR 64
#define DD 128
#define NPAIR 2016

__device__ __forceinline__ unsigned short f2bf_rne(float x) {
    unsigned int u = __float_as_uint(x);
    u += 0x7fffu + ((u >> 16) & 1u);
    return (unsigned short)(u >> 16);
}

// One block per batch. 256 threads = 4 waves. (Structure identical to the
// round-2 kernel that passed the full harness; only change: triangle-aware
// tj-skip in phase 2.)
//
// Phase 1: load X (64x128 fp32) coalesced, split into bf16 hi/lo, store to
//          XOR-swizzled LDS (elem ^= (row&7)<<3 == byte ^= (row&7)<<4; kills
//          the 16-way bank conflict of a linear [64][128] layout on the
//          stride-256B fragment reads).
// Phase 2: wave w computes row-strip ti=w of C = X*X^T via
//          mfma_f32_16x16x32_bf16, 3-term split (hi*hi + hi*lo + lo*hi).
//          Only column-tiles tj <= ti are computed: tj > ti holds no strictly
//          lower entries (c > r everywhere), so its MFMAs/ds_reads are waste.
//          Per-block MFMA 192 -> 120. ti is wave-constant -> clean exec-skip.
// Phase 3: write strictly-lower entries p = r*(r-1)/2 + c directly to global
//          (measured: LDS-staged burst epilogue was perf-neutral and is the
//          prime suspect for the round-4 post-timing divergence — reverted).
__global__ __launch_bounds__(256, 4) void dotint_kernel(const float* __restrict__ X,
                                                        float* __restrict__ out) {
    __shared__ __align__(16) unsigned short hi_s[KR * DD];
    __shared__ __align__(16) unsigned short lo_s[KR * DD];

    const int tid = threadIdx.x;
    const int b = blockIdx.x;
    const float* xb = X + (size_t)b * (KR * DD);

    // ---- Phase 1: load + hi/lo split ----
#pragma unroll
    for (int it = 0; it < 8; ++it) {
        const int e = it * 1024 + tid * 4;           // flat element index
        f32x4 v = *(const f32x4*)(xb + e);
        const int r = e >> 7;                        // row 0..63
        const int c = e & 127;                       // col, multiple of 4
        const int base = (r * DD + c) ^ ((r & 7) << 3);
        us4 h, l;
#pragma unroll
        for (int j = 0; j < 4; ++j) {
            const float x = v[j];
            const unsigned short hb = f2bf_rne(x);
            const float hf = __uint_as_float((unsigned int)hb << 16);
            const unsigned short lb = f2bf_rne(x - hf);
            h[j] = hb;
            l[j] = lb;
        }
        *(us4*)&hi_s[base] = h;
        *(us4*)&lo_s[base] = l;
    }
    __syncthreads();

    // ---- Phase 2: MFMA (only tj <= ti) ----
    const int w = tid >> 6;          // wave id 0..3 -> row-tile ti
    const int l = tid & 63;
    const int ti = w;
    const int arow = ti * 16 + (l & 15);
    const int kgrp = (l >> 4) * 8;   // this lane's 8 contiguous k's in a 32-chunk

    f32x4 acc[4];
#pragma unroll
    for (int tj = 0; tj < 4; ++tj) acc[tj] = (f32x4){0.f, 0.f, 0.f, 0.f};

#pragma unroll
    for (int ks = 0; ks < 4; ++ks) {
        const int kc = ks * 32 + kgrp;
        const int aidx = (arow * DD + kc) ^ ((arow & 7) << 3);
        const bf16x8 a_hi = *(const bf16x8*)&hi_s[aidx];
        const bf16x8 a_lo = *(const bf16x8*)&lo_s[aidx];
#pragma unroll
        for (int tj = 0; tj < 4; ++tj) {
            if (tj <= ti) {   // wave-constant guard: tj > ti has no r > c entries
                const int brow = tj * 16 + (l & 15);
                const int bidx = (brow * DD + kc) ^ ((brow & 7) << 3);
                const bf16x8 b_hi = *(const bf16x8*)&hi_s[bidx];
                const bf16x8 b_lo = *(const bf16x8*)&lo_s[bidx];
                acc[tj] = __builtin_amdgcn_mfma_f32_16x16x32_bf16(a_hi, b_hi, acc[tj], 0, 0, 0);
                acc[tj] = __builtin_amdgcn_mfma_f32_16x16x32_bf16(a_hi, b_lo, acc[tj], 0, 0, 0);
                acc[tj] = __builtin_amdgcn_mfma_f32_16x16x32_bf16(a_lo, b_hi, acc[tj], 0, 0, 0);
            }
        }
    }

    // ---- Phase 3: write strictly-lower triangle directly ----
    float* ob = out + (size_t)b * NPAIR;
    const int row0 = ti * 16 + (l >> 4) * 4;   // C/D layout: row=(lane>>4)*4+reg
    const int cl = l & 15;                     //             col=lane&15
#pragma unroll
    for (int tj = 0; tj < 4; ++tj) {
        const int c = tj * 16 + cl;
#pragma unroll
        for (int q = 0; q < 4; ++q) {
            const int r = row0 + q;
            if (r > c) ob[(r * (r - 1)) / 2 + c] = acc[tj][q];
        }
    }
}

extern "C" void kernel_launch(void* const* d_in, const int* in_sizes, int n_in,
                              void* d_out, int out_size, void* d_ws, size_t ws_size,
                              hipStream_t stream) {
    const float* X = (const float*)d_in[0];
    float* out = (float*)d_out;
    dotint_kernel<<<NB, 256, 0, stream>>>(X, out);
}